// Round 8
// baseline (131.835 us; speedup 1.0000x reference)
//
#include <hip/hip_runtime.h>
#include <hip/hip_bf16.h>
#include <cstdint>

typedef __hip_bfloat16 bf16;
using bf16x8 = __attribute__((ext_vector_type(8))) short;  // 8 bf16 (4 VGPRs)
using f32x4  = __attribute__((ext_vector_type(4))) float;

#define HW_T 4096   // H*W = 64*64
#define B_T  4

// async global->LDS, 16B per lane; LDS dest = wave-uniform base + lane*16
__device__ __forceinline__ void async_copy16(const bf16* g, bf16* l) {
    __builtin_amdgcn_global_load_lds(
        (const __attribute__((address_space(1))) void*)g,
        (__attribute__((address_space(3))) void*)l, 16, 0, 0);
}
__device__ __forceinline__ short f2bs(float f) {
    bf16 h = __float2bfloat16(f);
    return *reinterpret_cast<short*>(&h);
}
__device__ __forceinline__ float bs2f(short s) {
    unsigned int u = ((unsigned int)(unsigned short)s) << 16;
    float f;
    __builtin_memcpy(&f, &u, 4);
    return f;
}

// ---------------------------------------------------------------------------
// Prep (512 blocks):
//  blocks 0..383: fused weights W (384 x 256) bf16:
//   rows   0..63  : W[n*16+q, c] = sum_d dot_w[n,q,d] * kv_w[n*64+d, c]
//   rows  64..319 : W[64+n*64+dh, c] = sum_dd head_w[dh,n*64+dd]*kv_w[256+n*64+dd, c]
//   rows 320..383 : 0 (pad)
//  blocks 384..511: qwF fragment-layout convert:
//   qwF[(kb*256 + ch)*8 + j] = q_w[ch*1024 + kb*8 + j]   (kb = k>>3)
//   -> phase-2 A-fragment loads become 16-contiguous-line reads.
// ---------------------------------------------------------------------------
__global__ __launch_bounds__(256) void fuse_all(
    const float* __restrict__ kv_w, const float* __restrict__ dot_w,
    const float* __restrict__ head_w, const float* __restrict__ q_w,
    bf16* __restrict__ W, bf16* __restrict__ qwF)
{
    const int rb = blockIdx.x;
    if (rb < 384) {
        const int r = rb, c = threadIdx.x;
        float acc = 0.f;
        if (r < 64) {
            const int n = r >> 4, q = r & 15;
            #pragma unroll 8
            for (int d = 0; d < 64; ++d)
                acc += dot_w[(n * 16 + q) * 64 + d] * kv_w[(size_t)(n * 64 + d) * 256 + c];
        } else if (r < 320) {
            const int rr = r - 64, n = rr >> 6, dh = rr & 63;
            #pragma unroll 8
            for (int dd = 0; dd < 64; ++dd)
                acc += head_w[dh * 256 + n * 64 + dd] * kv_w[(size_t)(256 + n * 64 + dd) * 256 + c];
        }
        W[r * 256 + c] = __float2bfloat16(acc);
    } else {
        const int t  = (rb - 384) * 256 + threadIdx.x;  // 0..32767 = kb*256 + ch
        const int ch = t & 255, kb = t >> 8;
        const float* src = q_w + (size_t)ch * 1024 + kb * 8;
        bf16x8 pk;
        #pragma unroll
        for (int j = 0; j < 8; ++j) pk[j] = f2bs(src[j]);
        *(bf16x8*)&qwF[(size_t)t * 8] = pk;
    }
}

// ---------------------------------------------------------------------------
// K1: AH (b, p, 384) bf16 = x^T (on-the-fly transpose of fp32 x) * W^T.
// Tile 32(px) x 384(ch, full N), BK=32, 256 threads (4 waves, each 96 ch),
// double-buffered LDS, x read exactly once. Grid 128 x 4 = 512 blocks (2/CU).
// ---------------------------------------------------------------------------
__global__ __launch_bounds__(256) void gemm_xw(
    const float* __restrict__ x, const bf16* __restrict__ W,
    bf16* __restrict__ AH)
{
    __shared__ __align__(16) bf16 As[2][4][32][8];   // [buf][k>>3][px][k&7]  2x2KB
    __shared__ __align__(16) bf16 Bs[2][4][384][8];  // [buf][k>>3][ch][k&7]  2x24KB
    const int tid  = threadIdx.x;
    const int wave = tid >> 6, lane = tid & 63;
    const int p0 = blockIdx.x * 32;
    const int b  = blockIdx.y;
    const float* xb = x + (size_t)b * 256 * HW_T;
    const int fi = lane & 15, quad = lane >> 4;
    const int wn0 = wave * 96;

    const int apx = tid & 31, ac8 = (tid >> 5) & 3;  // A staging role (tid<128)
    const bool aStage = tid < 128;

    f32x4 acc[2][6] = {};
    float xr[8];

    // prologue: stage iter 0 into buf 0
    #pragma unroll
    for (int i = 0; i < 6; ++i) {
        const int s = i * 256 + tid;          // 0..1535
        const int ch = s % 384, q = s / 384;
        async_copy16(W + (size_t)ch * 256 + q * 8,
                     &Bs[0][0][0][0] + (size_t)(i * 256 + wave * 64) * 8);
    }
    if (aStage) {
        const float* xp = xb + (size_t)(ac8 * 8) * HW_T + p0 + apx;
        #pragma unroll
        for (int j = 0; j < 8; ++j) xr[j] = xp[(size_t)j * HW_T];
        bf16x8 pk;
        #pragma unroll
        for (int j = 0; j < 8; ++j) pk[j] = f2bs(xr[j]);
        *(bf16x8*)&As[0][ac8][apx][0] = pk;
    }

    for (int it = 0; it < 8; ++it) {
        const int cur = it & 1;
        __syncthreads();                       // buf[cur] ready
        if (it < 7) {
            const int k1 = (it + 1) * 32;
            #pragma unroll
            for (int i = 0; i < 6; ++i) {
                const int s = i * 256 + tid;
                const int ch = s % 384, q = s / 384;
                async_copy16(W + (size_t)ch * 256 + k1 + q * 8,
                             &Bs[cur ^ 1][0][0][0] + (size_t)(i * 256 + wave * 64) * 8);
            }
            if (aStage) {
                const float* xp = xb + (size_t)(k1 + ac8 * 8) * HW_T + p0 + apx;
                #pragma unroll
                for (int j = 0; j < 8; ++j) xr[j] = xp[(size_t)j * HW_T];
            }
        }
        bf16x8 af[2], bfr[6];
        #pragma unroll
        for (int i = 0; i < 2; ++i)
            af[i] = *(const bf16x8*)&As[cur][quad][i * 16 + fi][0];
        #pragma unroll
        for (int j = 0; j < 6; ++j)
            bfr[j] = *(const bf16x8*)&Bs[cur][quad][wn0 + j * 16 + fi][0];
        #pragma unroll
        for (int i = 0; i < 2; ++i)
            #pragma unroll
            for (int j = 0; j < 6; ++j)
                acc[i][j] = __builtin_amdgcn_mfma_f32_16x16x32_bf16(
                    af[i], bfr[j], acc[i][j], 0, 0, 0);
        if (it < 7 && aStage) {
            bf16x8 pk;
            #pragma unroll
            for (int j = 0; j < 8; ++j) pk[j] = f2bs(xr[j]);
            *(bf16x8*)&As[cur ^ 1][ac8][apx][0] = pk;
        }
    }

    bf16* Cp = AH + ((size_t)b * HW_T + p0) * 384;
    #pragma unroll
    for (int i = 0; i < 2; ++i) {
        const int pl = i * 16 + quad * 4;      // local pixel row
        #pragma unroll
        for (int r = 0; r < 4; ++r)
            #pragma unroll
            for (int j = 0; j < 6; ++j)
                Cp[(size_t)(pl + r) * 384 + wn0 + j * 16 + fi] =
                    __float2bfloat16(acc[i][j][r]);
    }
}

// ---------------------------------------------------------------------------
// Fused K4+K5: block = one image row (64 px), 512 threads (8 waves).
// AH (b,p,384) bf16: ch 0..63 = logits (n*16+q), ch 64..319 = hv (n*64+d).
// Phase 1 (8 px/wave, NO block barriers — P scratch is per-wave, same-wave DS
//   ops are in-order): softmax over 9 zero-padded window logits; y(16q x 64d)
//   = P(16x36) @ HV(36x64) as 4 MFMAs + fp32 tail; y -> LDS [64][1032] bf16.
// Phase 2: z tile (256 ch x 64 px, K=1024): A-fragments from qwF (fragment
//   layout -> 16-contiguous-line loads), B via ds_read_b128. No K-loop barriers.
// ---------------------------------------------------------------------------
#define YPAD 1032
#define ATTN_LDS (64 * YPAD * 2 + 8 * 9 * 64 * 4)   // 132096 + 18432 = 150528

__global__ __launch_bounds__(512) void attn_qy(
    const bf16* __restrict__ AH, const float* __restrict__ head_b,
    const bf16* __restrict__ qwF, const float* __restrict__ q_b,
    float* __restrict__ z)
{
    extern __shared__ __align__(16) char smem[];
    bf16*  yL = (bf16*)smem;                             // [64][YPAD]
    float* Pm = (float*)(smem + 64 * YPAD * 2) + (threadIdx.x >> 6) * 9 * 64;

    const int tid  = threadIdx.x;
    const int wave = tid >> 6, lane = tid & 63;
    const int p0  = blockIdx.x * 64;        // global pixel base (row-aligned)
    const int b   = p0 >> 12;
    const int hw0 = p0 & 4095;
    const int h   = hw0 >> 6;
    const int fi = lane & 15, quad = lane >> 4;
    const ushort* AHu = (const ushort*)AH;

    float hb[4];
    #pragma unroll
    for (int dt = 0; dt < 4; ++dt) hb[dt] = head_b[dt * 16 + fi];

    // ---------------- phase 1 (barrier-free; per-wave P scratch) ----------------
    for (int pi = 0; pi < 8; ++pi) {
        const int w = wave * 8 + pi;
        int off[9]; float okf[9];
        #pragma unroll
        for (int l = 0; l < 9; ++l) {
            const int i = l / 3, j = l % 3;
            const int hh = h + i - 1, ww = w + j - 1;
            const bool ok = ((unsigned)hh < 64u) && ((unsigned)ww < 64u);
            off[l] = ((b << 12) + (ok ? hh : h) * 64 + (ok ? ww : w)) * 384;
            okf[l] = ok ? 1.0f : 0.0f;
        }
        {   // softmax over zero-padded logits (lane = n*16+q)
            float lg[9];
            #pragma unroll
            for (int l = 0; l < 9; ++l)
                lg[l] = bs2f((short)AHu[(size_t)off[l] + lane]) * okf[l];
            float m = lg[0];
            #pragma unroll
            for (int l = 1; l < 9; ++l) m = fmaxf(m, lg[l]);
            float e[9], s = 0.f;
            #pragma unroll
            for (int l = 0; l < 9; ++l) { e[l] = __expf(lg[l] - m); s += e[l]; }
            const float inv = 1.0f / s;
            #pragma unroll
            for (int l = 0; l < 9; ++l) Pm[l * 64 + lane] = e[l] * inv * okf[l];
        }
        // same-wave DS write->read: in-order per wave; compiler inserts lgkmcnt

        // A-fragment: P[q=fi][k=quad*8+j], k=(l,n): l=k>>2, n=k&3 (l<8)
        bf16x8 afr;
        #pragma unroll
        for (int j = 0; j < 8; ++j) {
            const int k = quad * 8 + j;
            afr[j] = f2bs(Pm[(k >> 2) * 64 + (k & 3) * 16 + fi]);
        }
        f32x4 acc[4];
        #pragma unroll
        for (int dt = 0; dt < 4; ++dt) {
            acc[dt][0] = hb[dt]; acc[dt][1] = hb[dt];
            acc[dt][2] = hb[dt]; acc[dt][3] = hb[dt];
        }
        #pragma unroll
        for (int dt = 0; dt < 4; ++dt) {
            bf16x8 bfr;   // HV[k][d=dt*16+fi], already bf16 in AH
            #pragma unroll
            for (int j = 0; j < 8; ++j) {
                const int k = quad * 8 + j;
                bfr[j] = (short)AHu[(size_t)off[k >> 2] + 64 + (k & 3) * 64 + dt * 16 + fi];
            }
            acc[dt] = __builtin_amdgcn_mfma_f32_16x16x32_bf16(afr, bfr, acc[dt], 0, 0, 0);
        }
        // tail: l = 8, fp32
        #pragma unroll
        for (int n = 0; n < 4; ++n) {
            float pv[4];
            #pragma unroll
            for (int r = 0; r < 4; ++r) pv[r] = Pm[8 * 64 + n * 16 + quad * 4 + r];
            #pragma unroll
            for (int dt = 0; dt < 4; ++dt) {
                const float hval =
                    bs2f((short)AHu[(size_t)off[8] + 64 + n * 64 + dt * 16 + fi]);
                #pragma unroll
                for (int r = 0; r < 4; ++r) acc[dt][r] = fmaf(pv[r], hval, acc[dt][r]);
            }
        }
        // y -> LDS: yL[w][(quad*4+r)*64 + dt*16+fi]
        #pragma unroll
        for (int dt = 0; dt < 4; ++dt)
            #pragma unroll
            for (int r = 0; r < 4; ++r)
                yL[(size_t)w * YPAD + (quad * 4 + r) * 64 + dt * 16 + fi] =
                    __float2bfloat16(acc[dt][r]);
    }
    __syncthreads();   // y tile complete (cross-wave)

    // ---------------- phase 2: z = qw @ y^T + q_b ----------------
    f32x4 zacc[2][4] = {};
    bf16x8 af[2], afn[2];
    #pragma unroll
    for (int i = 0; i < 2; ++i)
        af[i] = *(const bf16x8*)&qwF[((size_t)quad * 256 + wave * 32 + i * 16 + fi) * 8];

    #pragma unroll 2
    for (int k0 = 0; k0 < 1024; k0 += 32) {
        if (k0 < 992) {
            const size_t kb = (size_t)((k0 + 32) >> 3) + quad;
            #pragma unroll
            for (int i = 0; i < 2; ++i)
                afn[i] = *(const bf16x8*)&qwF[(kb * 256 + wave * 32 + i * 16 + fi) * 8];
        }
        bf16x8 bfr[4];
        #pragma unroll
        for (int j = 0; j < 4; ++j)
            bfr[j] = *(const bf16x8*)&yL[(size_t)(j * 16 + fi) * YPAD + k0 + quad * 8];
        #pragma unroll
        for (int i = 0; i < 2; ++i)
            #pragma unroll
            for (int j = 0; j < 4; ++j)
                zacc[i][j] = __builtin_amdgcn_mfma_f32_16x16x32_bf16(
                    af[i], bfr[j], zacc[i][j], 0, 0, 0);
        af[0] = afn[0]; af[1] = afn[1];
    }

    #pragma unroll
    for (int i = 0; i < 2; ++i) {
        const int row0 = wave * 32 + i * 16 + quad * 4;
        #pragma unroll
        for (int r = 0; r < 4; ++r) {
            const float bv = q_b[row0 + r];
            #pragma unroll
            for (int j = 0; j < 4; ++j)
                z[((size_t)(b * 256 + row0 + r)) * HW_T + hw0 + j * 16 + fi] =
                    zacc[i][j][r] + bv;
        }
    }
}

// ---------------------------------------------------------------------------
extern "C" void kernel_launch(void* const* d_in, const int* in_sizes, int n_in,
                              void* d_out, int out_size, void* d_ws, size_t ws_size,
                              hipStream_t stream) {
    (void)in_sizes; (void)n_in; (void)out_size; (void)ws_size;
    const float* x      = (const float*)d_in[0];   // (4,256,64,64)
    const float* kv_w   = (const float*)d_in[1];   // (512,256)
    const float* dot_w  = (const float*)d_in[2];   // (4,16,64)
    const float* head_w = (const float*)d_in[3];   // (64,256)
    const float* head_b = (const float*)d_in[4];   // (64,)
    const float* q_w    = (const float*)d_in[5];   // (256,1024)
    const float* q_b    = (const float*)d_in[6];   // (256,)
    float* z = (float*)d_out;                      // (4,256,64,64)

    // workspace (13.3 MB):
    //   AH   bf16 (B,4096,384) 12582912 B @ 0
    //   W    bf16 (384,256)      196608 B @ 12582912
    //   qwF  bf16 (128,256,8)    524288 B @ 12779520   (fragment layout)
    char* ws   = (char*)d_ws;
    bf16*  AH  = (bf16*)ws;
    bf16*  W   = (bf16*)(ws + 12582912);
    bf16*  qwF = (bf16*)(ws + 12779520);

    // opt-in to >64KB dynamic LDS for the fused kernel (idempotent, host-side)
    static bool attr_done = []() {
        hipFuncSetAttribute((const void*)attn_qy,
                            hipFuncAttributeMaxDynamicSharedMemorySize, ATTN_LDS);
        return true;
    }();
    (void)attr_done;

    fuse_all<<<dim3(512), 256, 0, stream>>>(kv_w, dot_w, head_w, q_w, W, qwF);

    // K1: AH = x^T @ W^T  (M=4096/batch, N=384, K=256), transpose fused, bf16 out
    gemm_xw<<<dim3(128, B_T), 256, 0, stream>>>(x, W, AH);

    // K4+K5 fused: softmax/apply + z = qw @ y^T + q_b (y never leaves LDS)
    attn_qy<<<dim3(256), 512, ATTN_LDS, stream>>>(AH, head_b, qwF, q_b, z);
}

// Round 9
// 121.209 us; speedup vs baseline: 1.0877x; 1.0877x over previous
//
#include <hip/hip_runtime.h>
#include <hip/hip_bf16.h>
#include <cstdint>

typedef __hip_bfloat16 bf16;
using bf16x8 = __attribute__((ext_vector_type(8))) short;  // 8 bf16 (4 VGPRs)
using f32x4  = __attribute__((ext_vector_type(4))) float;

#define HW_T 4096   // H*W = 64*64
#define B_T  4

__device__ __forceinline__ short f2bs(float f) {
    bf16 h = __float2bfloat16(f);
    return *reinterpret_cast<short*>(&h);
}
__device__ __forceinline__ float bs2f(short s) {
    unsigned int u = ((unsigned int)(unsigned short)s) << 16;
    float f;
    __builtin_memcpy(&f, &u, 4);
    return f;
}

// ---------------------------------------------------------------------------
// Prep (448 blocks):
//  blocks 0..319: fused weight row rb, emitted directly in fragment layout:
//    Wf[(kb*320 + rb)*8 + (c&7)] = W_fused[rb][c],  kb = c>>3, c = tid
//    rows   0..63  : W[n*16+q, c] = sum_d dot_w[n,q,d] * kv_w[n*64+d, c]
//    rows  64..319 : W[64+n*64+dh, c] = sum_dd head_w[dh,n*64+dd]*kv_w[256+n*64+dd, c]
//  blocks 320..447: qwF fragment-layout convert:
//    qwF[(kb*256 + ch)*8 + j] = q_w[ch*1024 + kb*8 + j]
// ---------------------------------------------------------------------------
__global__ __launch_bounds__(256) void fuse_all(
    const float* __restrict__ kv_w, const float* __restrict__ dot_w,
    const float* __restrict__ head_w, const float* __restrict__ q_w,
    bf16* __restrict__ Wf, bf16* __restrict__ qwF)
{
    const int rb = blockIdx.x;
    if (rb < 320) {
        const int r = rb, c = threadIdx.x;
        float acc = 0.f;
        if (r < 64) {
            const int n = r >> 4, q = r & 15;
            #pragma unroll 8
            for (int d = 0; d < 64; ++d)
                acc += dot_w[(n * 16 + q) * 64 + d] * kv_w[(size_t)(n * 64 + d) * 256 + c];
        } else {
            const int rr = r - 64, n = rr >> 6, dh = rr & 63;
            #pragma unroll 8
            for (int dd = 0; dd < 64; ++dd)
                acc += head_w[dh * 256 + n * 64 + dd] * kv_w[(size_t)(256 + n * 64 + dd) * 256 + c];
        }
        Wf[((size_t)(c >> 3) * 320 + r) * 8 + (c & 7)] = __float2bfloat16(acc);
    } else {
        const int t  = (rb - 320) * 256 + threadIdx.x;  // 0..32767 = kb*256 + ch
        const int ch = t & 255, kb = t >> 8;
        const float* src = q_w + (size_t)ch * 1024 + kb * 8;
        bf16x8 pk;
        #pragma unroll
        for (int j = 0; j < 8; ++j) pk[j] = f2bs(src[j]);
        *(bf16x8*)&qwF[(size_t)t * 8] = pk;
    }
}

// ---------------------------------------------------------------------------
// K1: AH (b, p, 320) bf16 = x^T (on-the-fly transpose of fp32 x) * W^T.
// Tile 32 px x 320 ch (full N), BK=32, 256 threads (4 waves x 80 ch).
// LDS: only the 2 KB x tile (double-buffered). B-fragments stream directly
// from Wf in L2 with 1-iter register prefetch — no B staging, no W LDS.
// Grid 128 x 4 = 512 blocks (2 blocks/CU). x read exactly once.
// ---------------------------------------------------------------------------
__global__ __launch_bounds__(256) void gemm_xw(
    const float* __restrict__ x, const bf16* __restrict__ Wf,
    bf16* __restrict__ AH)
{
    __shared__ __align__(16) bf16 As[2][4][32][8];   // [buf][k>>3][px][k&7]  2x2KB
    const int tid  = threadIdx.x;
    const int lane = tid & 63;
    const int wave = tid >> 6;
    const int p0 = blockIdx.x * 32;
    const int b  = blockIdx.y;
    const float* xb = x + (size_t)b * 256 * HW_T;
    const int fi = lane & 15, quad = lane >> 4;
    const int wn0 = wave * 80;

    const int spx = tid & 31, sk = (tid >> 5) * 4;   // staging: pixel, k-base

    f32x4 acc[2][5] = {};
    float xr[4];
    bf16x8 bcur[5], bnxt[5];

    {   // prologue: stage iter 0 (A -> LDS buf0, B -> regs)
        const float* xp = xb + (size_t)sk * HW_T + p0 + spx;
        #pragma unroll
        for (int j = 0; j < 4; ++j) xr[j] = xp[(size_t)j * HW_T];
        #pragma unroll
        for (int j = 0; j < 5; ++j)
            bcur[j] = *(const bf16x8*)&Wf[((size_t)quad * 320 + wn0 + j * 16 + fi) * 8];
        short4 pk;
        pk.x = f2bs(xr[0]); pk.y = f2bs(xr[1]); pk.z = f2bs(xr[2]); pk.w = f2bs(xr[3]);
        *(short4*)&As[0][sk >> 3][spx][sk & 7] = pk;
    }

    for (int it = 0; it < 8; ++it) {
        const int cur = it & 1;
        __syncthreads();                       // As[cur] ready
        if (it < 7) {
            const int k1 = (it + 1) * 32;
            const float* xp = xb + (size_t)(k1 + sk) * HW_T + p0 + spx;
            #pragma unroll
            for (int j = 0; j < 4; ++j) xr[j] = xp[(size_t)j * HW_T];
            const size_t kb = (size_t)(k1 >> 3) + quad;
            #pragma unroll
            for (int j = 0; j < 5; ++j)
                bnxt[j] = *(const bf16x8*)&Wf[(kb * 320 + wn0 + j * 16 + fi) * 8];
        }
        bf16x8 af[2];
        #pragma unroll
        for (int i = 0; i < 2; ++i)
            af[i] = *(const bf16x8*)&As[cur][quad][i * 16 + fi][0];
        #pragma unroll
        for (int i = 0; i < 2; ++i)
            #pragma unroll
            for (int j = 0; j < 5; ++j)
                acc[i][j] = __builtin_amdgcn_mfma_f32_16x16x32_bf16(
                    af[i], bcur[j], acc[i][j], 0, 0, 0);
        if (it < 7) {
            short4 pk;
            pk.x = f2bs(xr[0]); pk.y = f2bs(xr[1]); pk.z = f2bs(xr[2]); pk.w = f2bs(xr[3]);
            *(short4*)&As[cur ^ 1][sk >> 3][spx][sk & 7] = pk;
            #pragma unroll
            for (int j = 0; j < 5; ++j) bcur[j] = bnxt[j];
        }
    }

    bf16* Cp = AH + ((size_t)b * HW_T + p0) * 320;
    #pragma unroll
    for (int i = 0; i < 2; ++i) {
        const int pl = i * 16 + quad * 4;      // local pixel row
        #pragma unroll
        for (int r = 0; r < 4; ++r)
            #pragma unroll
            for (int j = 0; j < 5; ++j)
                Cp[(size_t)(pl + r) * 320 + wn0 + j * 16 + fi] =
                    __float2bfloat16(acc[i][j][r]);
    }
}

// ---------------------------------------------------------------------------
// Fused K4+K5: block = one image row (64 px), 512 threads (8 waves).
// AH (b,p,320) bf16: ch 0..63 = logits (n*16+q), ch 64..319 = hv (n*64+d).
// Phase 1 (8 px/wave, per-pixel __syncthreads keeps waves lockstep on the
//   shared window rows -> L2 locality): softmax over 9 zero-padded window
//   logits; y(16q x 64d) = P(16x36) @ HV(36x64) as 4 MFMAs + fp32 tail;
//   y -> LDS [64][1032] bf16.
// Phase 2: z tile (256 ch x 64 px, K=1024): A-fragments from qwF (fragment
//   layout), B via ds_read_b128 from yL. No K-loop barriers.
// ---------------------------------------------------------------------------
#define YPAD 1032
#define ATTN_LDS (64 * YPAD * 2 + 8 * 9 * 64 * 4)   // 132096 + 18432 = 150528

__global__ __launch_bounds__(512) void attn_qy(
    const bf16* __restrict__ AH, const float* __restrict__ head_b,
    const bf16* __restrict__ qwF, const float* __restrict__ q_b,
    float* __restrict__ z)
{
    extern __shared__ __align__(16) char smem[];
    bf16*  yL = (bf16*)smem;                             // [64][YPAD]
    float* Pm = (float*)(smem + 64 * YPAD * 2) + (threadIdx.x >> 6) * 9 * 64;

    const int tid  = threadIdx.x;
    const int wave = tid >> 6, lane = tid & 63;
    const int p0  = blockIdx.x * 64;        // global pixel base (row-aligned)
    const int b   = p0 >> 12;
    const int hw0 = p0 & 4095;
    const int h   = hw0 >> 6;
    const int fi = lane & 15, quad = lane >> 4;
    const ushort* AHu = (const ushort*)AH;

    float hb[4];
    #pragma unroll
    for (int dt = 0; dt < 4; ++dt) hb[dt] = head_b[dt * 16 + fi];

    // ---------------- phase 1 ----------------
    for (int pi = 0; pi < 8; ++pi) {
        const int w = wave * 8 + pi;
        int off[9]; float okf[9];
        #pragma unroll
        for (int l = 0; l < 9; ++l) {
            const int i = l / 3, j = l % 3;
            const int hh = h + i - 1, ww = w + j - 1;
            const bool ok = ((unsigned)hh < 64u) && ((unsigned)ww < 64u);
            off[l] = ((b << 12) + (ok ? hh : h) * 64 + (ok ? ww : w)) * 320;
            okf[l] = ok ? 1.0f : 0.0f;
        }
        {   // softmax over zero-padded logits (lane = n*16+q)
            float lg[9];
            #pragma unroll
            for (int l = 0; l < 9; ++l)
                lg[l] = bs2f((short)AHu[(size_t)off[l] + lane]) * okf[l];
            float m = lg[0];
            #pragma unroll
            for (int l = 1; l < 9; ++l) m = fmaxf(m, lg[l]);
            float e[9], s = 0.f;
            #pragma unroll
            for (int l = 0; l < 9; ++l) { e[l] = __expf(lg[l] - m); s += e[l]; }
            const float inv = 1.0f / s;
            #pragma unroll
            for (int l = 0; l < 9; ++l) Pm[l * 64 + lane] = e[l] * inv * okf[l];
        }
        __syncthreads();   // keep 8 waves lockstep (shared window rows in L2)

        // A-fragment: P[q=fi][k=quad*8+j], k=(l,n): l=k>>2, n=k&3 (l<8)
        bf16x8 afr;
        #pragma unroll
        for (int j = 0; j < 8; ++j) {
            const int k = quad * 8 + j;
            afr[j] = f2bs(Pm[(k >> 2) * 64 + (k & 3) * 16 + fi]);
        }
        f32x4 acc[4];
        #pragma unroll
        for (int dt = 0; dt < 4; ++dt) {
            acc[dt][0] = hb[dt]; acc[dt][1] = hb[dt];
            acc[dt][2] = hb[dt]; acc[dt][3] = hb[dt];
        }
        #pragma unroll
        for (int dt = 0; dt < 4; ++dt) {
            bf16x8 bfr;   // HV[k][d=dt*16+fi], already bf16 in AH
            #pragma unroll
            for (int j = 0; j < 8; ++j) {
                const int k = quad * 8 + j;
                bfr[j] = (short)AHu[(size_t)off[k >> 2] + 64 + (k & 3) * 64 + dt * 16 + fi];
            }
            acc[dt] = __builtin_amdgcn_mfma_f32_16x16x32_bf16(afr, bfr, acc[dt], 0, 0, 0);
        }
        // tail: l = 8, fp32
        #pragma unroll
        for (int n = 0; n < 4; ++n) {
            float pv[4];
            #pragma unroll
            for (int r = 0; r < 4; ++r) pv[r] = Pm[8 * 64 + n * 16 + quad * 4 + r];
            #pragma unroll
            for (int dt = 0; dt < 4; ++dt) {
                const float hval =
                    bs2f((short)AHu[(size_t)off[8] + 64 + n * 64 + dt * 16 + fi]);
                #pragma unroll
                for (int r = 0; r < 4; ++r) acc[dt][r] = fmaf(pv[r], hval, acc[dt][r]);
            }
        }
        // y -> LDS: yL[w][(quad*4+r)*64 + dt*16+fi]
        #pragma unroll
        for (int dt = 0; dt < 4; ++dt)
            #pragma unroll
            for (int r = 0; r < 4; ++r)
                yL[(size_t)w * YPAD + (quad * 4 + r) * 64 + dt * 16 + fi] =
                    __float2bfloat16(acc[dt][r]);
    }
    __syncthreads();   // y tile complete (cross-wave)

    // ---------------- phase 2: z = qw @ y^T + q_b ----------------
    f32x4 zacc[2][4] = {};
    bf16x8 af[2], afn[2];
    #pragma unroll
    for (int i = 0; i < 2; ++i)
        af[i] = *(const bf16x8*)&qwF[((size_t)quad * 256 + wave * 32 + i * 16 + fi) * 8];

    #pragma unroll 2
    for (int k0 = 0; k0 < 1024; k0 += 32) {
        if (k0 < 992) {
            const size_t kb = (size_t)((k0 + 32) >> 3) + quad;
            #pragma unroll
            for (int i = 0; i < 2; ++i)
                afn[i] = *(const bf16x8*)&qwF[(kb * 256 + wave * 32 + i * 16 + fi) * 8];
        }
        bf16x8 bfr[4];
        #pragma unroll
        for (int j = 0; j < 4; ++j)
            bfr[j] = *(const bf16x8*)&yL[(size_t)(j * 16 + fi) * YPAD + k0 + quad * 8];
        #pragma unroll
        for (int i = 0; i < 2; ++i)
            #pragma unroll
            for (int j = 0; j < 4; ++j)
                zacc[i][j] = __builtin_amdgcn_mfma_f32_16x16x32_bf16(
                    af[i], bfr[j], zacc[i][j], 0, 0, 0);
        af[0] = afn[0]; af[1] = afn[1];
    }

    #pragma unroll
    for (int i = 0; i < 2; ++i) {
        const int row0 = wave * 32 + i * 16 + quad * 4;
        #pragma unroll
        for (int r = 0; r < 4; ++r) {
            const float bv = q_b[row0 + r];
            #pragma unroll
            for (int j = 0; j < 4; ++j)
                z[((size_t)(b * 256 + row0 + r)) * HW_T + hw0 + j * 16 + fi] =
                    zacc[i][j][r] + bv;
        }
    }
}

// ---------------------------------------------------------------------------
extern "C" void kernel_launch(void* const* d_in, const int* in_sizes, int n_in,
                              void* d_out, int out_size, void* d_ws, size_t ws_size,
                              hipStream_t stream) {
    (void)in_sizes; (void)n_in; (void)out_size; (void)ws_size;
    const float* x      = (const float*)d_in[0];   // (4,256,64,64)
    const float* kv_w   = (const float*)d_in[1];   // (512,256)
    const float* dot_w  = (const float*)d_in[2];   // (4,16,64)
    const float* head_w = (const float*)d_in[3];   // (64,256)
    const float* head_b = (const float*)d_in[4];   // (64,)
    const float* q_w    = (const float*)d_in[5];   // (256,1024)
    const float* q_b    = (const float*)d_in[6];   // (256,)
    float* z = (float*)d_out;                      // (4,256,64,64)

    // workspace (11.2 MB):
    //   AH   bf16 (B,4096,320) 10485760 B @ 0
    //   qwF  bf16 (128,256,8)    524288 B @ 10485760
    //   Wf   bf16 (32,320,8)     163840 B @ 11010048
    char* ws   = (char*)d_ws;
    bf16*  AH  = (bf16*)ws;
    bf16*  qwF = (bf16*)(ws + 10485760);
    bf16*  Wf  = (bf16*)(ws + 11010048);

    // opt-in to >64KB dynamic LDS for the fused kernel (idempotent, host-side)
    static bool attr_done = []() {
        hipFuncSetAttribute((const void*)attn_qy,
                            hipFuncAttributeMaxDynamicSharedMemorySize, ATTN_LDS);
        return true;
    }();
    (void)attr_done;

    fuse_all<<<dim3(448), 256, 0, stream>>>(kv_w, dot_w, head_w, q_w, Wf, qwF);

    // K1: AH = x^T @ W^T  (M=4096/batch, N=320, K=256), transpose fused, bf16 out
    gemm_xw<<<dim3(128, B_T), 256, 0, stream>>>(x, Wf, AH);

    // K4+K5 fused: softmax/apply + z = qw @ y^T + q_b (y never leaves LDS)
    attn_qy<<<dim3(256), 512, ATTN_LDS, stream>>>(AH, head_b, qwF, q_b, z);
}

// Round 10
// 113.000 us; speedup vs baseline: 1.1667x; 1.0727x over previous
//
#include <hip/hip_runtime.h>
#include <hip/hip_bf16.h>
#include <cstdint>

typedef __hip_bfloat16 bf16;
using bf16x8 = __attribute__((ext_vector_type(8))) short;  // 8 bf16 (4 VGPRs)
using f32x4  = __attribute__((ext_vector_type(4))) float;

#define HW_T 4096   // H*W = 64*64
#define B_T  4

__device__ __forceinline__ short f2bs(float f) {
    bf16 h = __float2bfloat16(f);
    return *reinterpret_cast<short*>(&h);
}
__device__ __forceinline__ float bs2f(short s) {
    unsigned int u = ((unsigned int)(unsigned short)s) << 16;
    float f;
    __builtin_memcpy(&f, &u, 4);
    return f;
}

// ---------------------------------------------------------------------------
// Prep (448 blocks):
//  blocks 0..319: fused weight row rb, emitted directly in fragment layout:
//    Wf[(kb*320 + rb)*8 + (c&7)] = W_fused[rb][c],  kb = c>>3, c = tid
//    rows   0..63  : W[n*16+q, c] = sum_d dot_w[n,q,d] * kv_w[n*64+d, c]
//    rows  64..319 : W[64+n*64+dh, c] = sum_dd head_w[dh,n*64+dd]*kv_w[256+n*64+dd, c]
//  blocks 320..447: qwF fragment-layout convert:
//    qwF[(kb*256 + ch)*8 + j] = q_w[ch*1024 + kb*8 + j]
// ---------------------------------------------------------------------------
__global__ __launch_bounds__(256) void fuse_all(
    const float* __restrict__ kv_w, const float* __restrict__ dot_w,
    const float* __restrict__ head_w, const float* __restrict__ q_w,
    bf16* __restrict__ Wf, bf16* __restrict__ qwF)
{
    const int rb = blockIdx.x;
    if (rb < 320) {
        const int r = rb, c = threadIdx.x;
        float acc = 0.f;
        if (r < 64) {
            const int n = r >> 4, q = r & 15;
            #pragma unroll 8
            for (int d = 0; d < 64; ++d)
                acc += dot_w[(n * 16 + q) * 64 + d] * kv_w[(size_t)(n * 64 + d) * 256 + c];
        } else {
            const int rr = r - 64, n = rr >> 6, dh = rr & 63;
            #pragma unroll 8
            for (int dd = 0; dd < 64; ++dd)
                acc += head_w[dh * 256 + n * 64 + dd] * kv_w[(size_t)(256 + n * 64 + dd) * 256 + c];
        }
        Wf[((size_t)(c >> 3) * 320 + r) * 8 + (c & 7)] = __float2bfloat16(acc);
    } else {
        const int t  = (rb - 320) * 256 + threadIdx.x;  // 0..32767 = kb*256 + ch
        const int ch = t & 255, kb = t >> 8;
        const float* src = q_w + (size_t)ch * 1024 + kb * 8;
        bf16x8 pk;
        #pragma unroll
        for (int j = 0; j < 8; ++j) pk[j] = f2bs(src[j]);
        *(bf16x8*)&qwF[(size_t)t * 8] = pk;
    }
}

// ---------------------------------------------------------------------------
// K1: AH (b, p, 320) bf16 = x^T (on-the-fly transpose of fp32 x) * W^T.
// Tile 32 px x 320 ch (full N), BK=32, 256 threads (4 waves x 80 ch).
// LDS: only the 2 KB x tile (double-buffered). B-fragments stream directly
// from Wf in L2 with 1-iter register prefetch. Grid 128 x 4 (2 blocks/CU).
// ---------------------------------------------------------------------------
__global__ __launch_bounds__(256) void gemm_xw(
    const float* __restrict__ x, const bf16* __restrict__ Wf,
    bf16* __restrict__ AH)
{
    __shared__ __align__(16) bf16 As[2][4][32][8];   // [buf][k>>3][px][k&7]  2x2KB
    const int tid  = threadIdx.x;
    const int lane = tid & 63;
    const int wave = tid >> 6;
    const int p0 = blockIdx.x * 32;
    const int b  = blockIdx.y;
    const float* xb = x + (size_t)b * 256 * HW_T;
    const int fi = lane & 15, quad = lane >> 4;
    const int wn0 = wave * 80;

    const int spx = tid & 31, sk = (tid >> 5) * 4;   // staging: pixel, k-base

    f32x4 acc[2][5] = {};
    float xr[4];
    bf16x8 bcur[5], bnxt[5];

    {   // prologue: stage iter 0 (A -> LDS buf0, B -> regs)
        const float* xp = xb + (size_t)sk * HW_T + p0 + spx;
        #pragma unroll
        for (int j = 0; j < 4; ++j) xr[j] = xp[(size_t)j * HW_T];
        #pragma unroll
        for (int j = 0; j < 5; ++j)
            bcur[j] = *(const bf16x8*)&Wf[((size_t)quad * 320 + wn0 + j * 16 + fi) * 8];
        short4 pk;
        pk.x = f2bs(xr[0]); pk.y = f2bs(xr[1]); pk.z = f2bs(xr[2]); pk.w = f2bs(xr[3]);
        *(short4*)&As[0][sk >> 3][spx][sk & 7] = pk;
    }

    for (int it = 0; it < 8; ++it) {
        const int cur = it & 1;
        __syncthreads();                       // As[cur] ready
        if (it < 7) {
            const int k1 = (it + 1) * 32;
            const float* xp = xb + (size_t)(k1 + sk) * HW_T + p0 + spx;
            #pragma unroll
            for (int j = 0; j < 4; ++j) xr[j] = xp[(size_t)j * HW_T];
            const size_t kb = (size_t)(k1 >> 3) + quad;
            #pragma unroll
            for (int j = 0; j < 5; ++j)
                bnxt[j] = *(const bf16x8*)&Wf[(kb * 320 + wn0 + j * 16 + fi) * 8];
        }
        bf16x8 af[2];
        #pragma unroll
        for (int i = 0; i < 2; ++i)
            af[i] = *(const bf16x8*)&As[cur][quad][i * 16 + fi][0];
        #pragma unroll
        for (int i = 0; i < 2; ++i)
            #pragma unroll
            for (int j = 0; j < 5; ++j)
                acc[i][j] = __builtin_amdgcn_mfma_f32_16x16x32_bf16(
                    af[i], bcur[j], acc[i][j], 0, 0, 0);
        if (it < 7) {
            short4 pk;
            pk.x = f2bs(xr[0]); pk.y = f2bs(xr[1]); pk.z = f2bs(xr[2]); pk.w = f2bs(xr[3]);
            *(short4*)&As[cur ^ 1][sk >> 3][spx][sk & 7] = pk;
            #pragma unroll
            for (int j = 0; j < 5; ++j) bcur[j] = bnxt[j];
        }
    }

    bf16* Cp = AH + ((size_t)b * HW_T + p0) * 320;
    #pragma unroll
    for (int i = 0; i < 2; ++i) {
        const int pl = i * 16 + quad * 4;      // local pixel row
        #pragma unroll
        for (int r = 0; r < 4; ++r)
            #pragma unroll
            for (int j = 0; j < 5; ++j)
                Cp[(size_t)(pl + r) * 320 + wn0 + j * 16 + fi] =
                    __float2bfloat16(acc[i][j][r]);
    }
}

// ---------------------------------------------------------------------------
// Fused K4+K5: block = 32-px half-row, 256 threads (4 waves, 8 px/wave).
// Grid 512 (2 blocks/CU -> cross-block phase1/phase2 overlap).
// AH (b,p,320) bf16: ch 0..63 = logits (n*16+q), ch 64..319 = hv (n*64+d).
// Phase 1 (NO block barriers — P scratch is per-wave; same-wave DS ops are
//   in-order): softmax over 9 zero-padded window logits; y(16q x 64d) =
//   P(16x36) @ HV(36x64) as 4 MFMAs + fp32 tail; y -> LDS [32][1032] bf16.
// Phase 2: z tile (256 ch x 32 px, K=1024): wave owns 64 ch; A-fragments from
//   qwF (fragment layout, register prefetch), B via ds_read_b128 from yL.
//   Single barrier between phases; no K-loop barriers.
// ---------------------------------------------------------------------------
#define YPAD 1032
#define ATTN_LDS (32 * YPAD * 2 + 4 * 9 * 64 * 4)   // 66048 + 9216 = 75264

__global__ __launch_bounds__(256) void attn_qy(
    const bf16* __restrict__ AH, const float* __restrict__ head_b,
    const bf16* __restrict__ qwF, const float* __restrict__ q_b,
    float* __restrict__ z)
{
    extern __shared__ __align__(16) char smem[];
    bf16*  yL = (bf16*)smem;                             // [32][YPAD]
    float* Pm = (float*)(smem + 32 * YPAD * 2) + (threadIdx.x >> 6) * 9 * 64;

    const int tid  = threadIdx.x;
    const int wave = tid >> 6, lane = tid & 63;
    const int half = blockIdx.x & 1;
    const int h    = (blockIdx.x >> 1) & 63;
    const int b    = blockIdx.x >> 7;
    const int w0   = half * 32;
    const int hw0  = h * 64 + w0;
    const int fi = lane & 15, quad = lane >> 4;
    const ushort* AHu = (const ushort*)AH;

    float hb[4];
    #pragma unroll
    for (int dt = 0; dt < 4; ++dt) hb[dt] = head_b[dt * 16 + fi];

    // ---------------- phase 1 (barrier-free) ----------------
    for (int pi = 0; pi < 8; ++pi) {
        const int lp = wave * 8 + pi;      // local pixel 0..31
        const int w  = w0 + lp;
        int off[9]; float okf[9];
        #pragma unroll
        for (int l = 0; l < 9; ++l) {
            const int i = l / 3, j = l % 3;
            const int hh = h + i - 1, ww = w + j - 1;
            const bool ok = ((unsigned)hh < 64u) && ((unsigned)ww < 64u);
            off[l] = ((b << 12) + (ok ? hh : h) * 64 + (ok ? ww : w)) * 320;
            okf[l] = ok ? 1.0f : 0.0f;
        }
        {   // softmax over zero-padded logits (lane = n*16+q)
            float lg[9];
            #pragma unroll
            for (int l = 0; l < 9; ++l)
                lg[l] = bs2f((short)AHu[(size_t)off[l] + lane]) * okf[l];
            float m = lg[0];
            #pragma unroll
            for (int l = 1; l < 9; ++l) m = fmaxf(m, lg[l]);
            float e[9], s = 0.f;
            #pragma unroll
            for (int l = 0; l < 9; ++l) { e[l] = __expf(lg[l] - m); s += e[l]; }
            const float inv = 1.0f / s;
            #pragma unroll
            for (int l = 0; l < 9; ++l) Pm[l * 64 + lane] = e[l] * inv * okf[l];
        }
        // same-wave DS write->read is in-order; no barrier needed

        // A-fragment: P[q=fi][k=quad*8+j], k=(l,n): l=k>>2, n=k&3 (l<8)
        bf16x8 afr;
        #pragma unroll
        for (int j = 0; j < 8; ++j) {
            const int k = quad * 8 + j;
            afr[j] = f2bs(Pm[(k >> 2) * 64 + (k & 3) * 16 + fi]);
        }
        f32x4 acc[4];
        #pragma unroll
        for (int dt = 0; dt < 4; ++dt) {
            acc[dt][0] = hb[dt]; acc[dt][1] = hb[dt];
            acc[dt][2] = hb[dt]; acc[dt][3] = hb[dt];
        }
        #pragma unroll
        for (int dt = 0; dt < 4; ++dt) {
            bf16x8 bfr;   // HV[k][d=dt*16+fi], already bf16 in AH
            #pragma unroll
            for (int j = 0; j < 8; ++j) {
                const int k = quad * 8 + j;
                bfr[j] = (short)AHu[(size_t)off[k >> 2] + 64 + (k & 3) * 64 + dt * 16 + fi];
            }
            acc[dt] = __builtin_amdgcn_mfma_f32_16x16x32_bf16(afr, bfr, acc[dt], 0, 0, 0);
        }
        // tail: l = 8, fp32
        #pragma unroll
        for (int n = 0; n < 4; ++n) {
            float pv[4];
            #pragma unroll
            for (int r = 0; r < 4; ++r) pv[r] = Pm[8 * 64 + n * 16 + quad * 4 + r];
            #pragma unroll
            for (int dt = 0; dt < 4; ++dt) {
                const float hval =
                    bs2f((short)AHu[(size_t)off[8] + 64 + n * 64 + dt * 16 + fi]);
                #pragma unroll
                for (int r = 0; r < 4; ++r) acc[dt][r] = fmaf(pv[r], hval, acc[dt][r]);
            }
        }
        // y -> LDS: yL[lp][(quad*4+r)*64 + dt*16+fi]
        #pragma unroll
        for (int dt = 0; dt < 4; ++dt)
            #pragma unroll
            for (int r = 0; r < 4; ++r)
                yL[(size_t)lp * YPAD + (quad * 4 + r) * 64 + dt * 16 + fi] =
                    __float2bfloat16(acc[dt][r]);
    }
    __syncthreads();   // y tile complete (cross-wave)

    // ---------------- phase 2: z = qw @ y^T + q_b ----------------
    f32x4 zacc[4][2] = {};
    bf16x8 af[4], afn[4];
    #pragma unroll
    for (int i = 0; i < 4; ++i)
        af[i] = *(const bf16x8*)&qwF[((size_t)quad * 256 + wave * 64 + i * 16 + fi) * 8];

    #pragma unroll 2
    for (int k0 = 0; k0 < 1024; k0 += 32) {
        if (k0 < 992) {
            const size_t kb = (size_t)((k0 + 32) >> 3) + quad;
            #pragma unroll
            for (int i = 0; i < 4; ++i)
                afn[i] = *(const bf16x8*)&qwF[(kb * 256 + wave * 64 + i * 16 + fi) * 8];
        }
        bf16x8 bfr[2];
        #pragma unroll
        for (int j = 0; j < 2; ++j)
            bfr[j] = *(const bf16x8*)&yL[(size_t)(j * 16 + fi) * YPAD + k0 + quad * 8];
        #pragma unroll
        for (int i = 0; i < 4; ++i)
            #pragma unroll
            for (int j = 0; j < 2; ++j)
                zacc[i][j] = __builtin_amdgcn_mfma_f32_16x16x32_bf16(
                    af[i], bfr[j], zacc[i][j], 0, 0, 0);
        #pragma unroll
        for (int i = 0; i < 4; ++i) af[i] = afn[i];
    }

    #pragma unroll
    for (int i = 0; i < 4; ++i) {
        const int row0 = wave * 64 + i * 16 + quad * 4;
        #pragma unroll
        for (int r = 0; r < 4; ++r) {
            const float bv = q_b[row0 + r];
            #pragma unroll
            for (int j = 0; j < 2; ++j)
                z[((size_t)(b * 256 + row0 + r)) * HW_T + hw0 + j * 16 + fi] =
                    zacc[i][j][r] + bv;
        }
    }
}

// ---------------------------------------------------------------------------
extern "C" void kernel_launch(void* const* d_in, const int* in_sizes, int n_in,
                              void* d_out, int out_size, void* d_ws, size_t ws_size,
                              hipStream_t stream) {
    (void)in_sizes; (void)n_in; (void)out_size; (void)ws_size;
    const float* x      = (const float*)d_in[0];   // (4,256,64,64)
    const float* kv_w   = (const float*)d_in[1];   // (512,256)
    const float* dot_w  = (const float*)d_in[2];   // (4,16,64)
    const float* head_w = (const float*)d_in[3];   // (64,256)
    const float* head_b = (const float*)d_in[4];   // (64,)
    const float* q_w    = (const float*)d_in[5];   // (256,1024)
    const float* q_b    = (const float*)d_in[6];   // (256,)
    float* z = (float*)d_out;                      // (4,256,64,64)

    // workspace (11.2 MB):
    //   AH   bf16 (B,4096,320) 10485760 B @ 0
    //   qwF  bf16 (128,256,8)    524288 B @ 10485760
    //   Wf   bf16 (32,320,8)     163840 B @ 11010048
    char* ws   = (char*)d_ws;
    bf16*  AH  = (bf16*)ws;
    bf16*  qwF = (bf16*)(ws + 10485760);
    bf16*  Wf  = (bf16*)(ws + 11010048);

    // opt-in to >64KB dynamic LDS for the fused kernel (idempotent, host-side)
    static bool attr_done = []() {
        hipFuncSetAttribute((const void*)attn_qy,
                            hipFuncAttributeMaxDynamicSharedMemorySize, ATTN_LDS);
        return true;
    }();
    (void)attr_done;

    fuse_all<<<dim3(448), 256, 0, stream>>>(kv_w, dot_w, head_w, q_w, Wf, qwF);

    // K1: AH = x^T @ W^T  (M=4096/batch, N=320, K=256), transpose fused, bf16 out
    gemm_xw<<<dim3(128, B_T), 256, 0, stream>>>(x, Wf, AH);

    // K4+K5 fused: softmax/apply + z = qw @ y^T + q_b (y never leaves LDS)
    attn_qy<<<dim3(512), 256, ATTN_LDS, stream>>>(AH, head_b, qwF, q_b, z);
}

// Round 11
// 112.724 us; speedup vs baseline: 1.1695x; 1.0025x over previous
//
#include <hip/hip_runtime.h>
#include <hip/hip_bf16.h>
#include <cstdint>

typedef __hip_bfloat16 bf16;
using bf16x8 = __attribute__((ext_vector_type(8))) short;  // 8 bf16 (4 VGPRs)
using f32x4  = __attribute__((ext_vector_type(4))) float;

#define HW_T 4096   // H*W = 64*64
#define B_T  4

__device__ __forceinline__ short f2bs(float f) {
    bf16 h = __float2bfloat16(f);
    return *reinterpret_cast<short*>(&h);
}
__device__ __forceinline__ float bs2f(unsigned short s) {
    unsigned int u = ((unsigned int)s) << 16;
    float f;
    __builtin_memcpy(&f, &u, 4);
    return f;
}

// ---------------------------------------------------------------------------
// Prep (448 blocks):
//  blocks 0..319: fused weight row, emitted in fragment layout Wf[kb][row][8].
//   HV rows are stored INTERLEAVED: row 64 + dh*4 + n  (so attn_qy reads
//   HV[n=0..3] for fixed (l, dh) as one contiguous b64).
//    logits: row n*16+q      = sum_d dot_w[n,q,d] * kv_w[n*64+d, c]
//    hv:     row 64+dh*4+n   = sum_dd head_w[dh, n*64+dd] * kv_w[256+n*64+dd, c]
//  blocks 320..447: qwF fragment-layout convert:
//    qwF[(kb*256 + ch)*8 + j] = q_w[ch*1024 + kb*8 + j]
// ---------------------------------------------------------------------------
__global__ __launch_bounds__(256) void fuse_all(
    const float* __restrict__ kv_w, const float* __restrict__ dot_w,
    const float* __restrict__ head_w, const float* __restrict__ q_w,
    bf16* __restrict__ Wf, bf16* __restrict__ qwF)
{
    const int rb = blockIdx.x;
    if (rb < 320) {
        const int r = rb, c = threadIdx.x;
        float acc = 0.f;
        int rowIdx;
        if (r < 64) {
            const int n = r >> 4, q = r & 15;
            #pragma unroll 8
            for (int d = 0; d < 64; ++d)
                acc += dot_w[(n * 16 + q) * 64 + d] * kv_w[(size_t)(n * 64 + d) * 256 + c];
            rowIdx = r;
        } else {
            const int rr = r - 64, n = rr >> 6, dh = rr & 63;
            #pragma unroll 8
            for (int dd = 0; dd < 64; ++dd)
                acc += head_w[dh * 256 + n * 64 + dd] * kv_w[(size_t)(256 + n * 64 + dd) * 256 + c];
            rowIdx = 64 + dh * 4 + n;   // interleaved HV layout
        }
        Wf[((size_t)(c >> 3) * 320 + rowIdx) * 8 + (c & 7)] = __float2bfloat16(acc);
    } else {
        const int t  = (rb - 320) * 256 + threadIdx.x;  // 0..32767 = kb*256 + ch
        const int ch = t & 255, kb = t >> 8;
        const float* src = q_w + (size_t)ch * 1024 + kb * 8;
        bf16x8 pk;
        #pragma unroll
        for (int j = 0; j < 8; ++j) pk[j] = f2bs(src[j]);
        *(bf16x8*)&qwF[(size_t)t * 8] = pk;
    }
}

// ---------------------------------------------------------------------------
// K1: AH (b, p, 320) bf16 = x^T (on-the-fly transpose of fp32 x) * W^T.
// Tile 32 px x 320 ch (full N), BK=64, 256 threads (4 waves x 80 ch), fully
// unrolled 4-iter K-loop, double-buffered 4KB A tile (one ds_write_b128 per
// thread per iter), B-fragments streamed from Wf in L2 with register
// prefetch. 2 KB/wave of x-loads in flight per iter. Grid 128 x 4 (2/CU).
// ---------------------------------------------------------------------------
__global__ __launch_bounds__(256) void gemm_xw(
    const float* __restrict__ x, const bf16* __restrict__ Wf,
    bf16* __restrict__ AH)
{
    __shared__ __align__(16) bf16 As[2][8][32][8];   // [buf][ch8][px][ch&7] 2x4KB
    const int tid  = threadIdx.x;
    const int lane = tid & 63;
    const int wave = tid >> 6;
    const int p0 = blockIdx.x * 32;
    const int b  = blockIdx.y;
    const float* xb = x + (size_t)b * 256 * HW_T;
    const int fi = lane & 15, quad = lane >> 4;
    const int wn0 = wave * 80;

    const int spx = tid & 31, sc8 = tid >> 5;   // staging: pixel, ch-octet 0..7

    f32x4 acc[2][5] = {};
    float xr[8];
    bf16x8 bcur[2][5], bnxt[2][5];

    {   // prologue: stage iter 0 (A -> LDS buf0, B -> regs)
        const float* xp = xb + (size_t)(sc8 * 8) * HW_T + p0 + spx;
        #pragma unroll
        for (int j = 0; j < 8; ++j) xr[j] = xp[(size_t)j * HW_T];
        #pragma unroll
        for (int c = 0; c < 2; ++c)
            #pragma unroll
            for (int j = 0; j < 5; ++j)
                bcur[c][j] = *(const bf16x8*)
                    &Wf[((size_t)(c * 4 + quad) * 320 + wn0 + j * 16 + fi) * 8];
        bf16x8 pk;
        #pragma unroll
        for (int j = 0; j < 8; ++j) pk[j] = f2bs(xr[j]);
        *(bf16x8*)&As[0][sc8][spx][0] = pk;
    }

    #pragma unroll
    for (int it = 0; it < 4; ++it) {
        const int cur = it & 1;
        __syncthreads();                       // As[cur] ready
        if (it < 3) {
            const int k1 = (it + 1) * 64;
            const float* xp = xb + (size_t)(k1 + sc8 * 8) * HW_T + p0 + spx;
            #pragma unroll
            for (int j = 0; j < 8; ++j) xr[j] = xp[(size_t)j * HW_T];
            #pragma unroll
            for (int c = 0; c < 2; ++c)
                #pragma unroll
                for (int j = 0; j < 5; ++j)
                    bnxt[c][j] = *(const bf16x8*)
                        &Wf[((size_t)((k1 >> 3) + c * 4 + quad) * 320 + wn0 + j * 16 + fi) * 8];
        }
        #pragma unroll
        for (int c = 0; c < 2; ++c) {
            bf16x8 af[2];
            #pragma unroll
            for (int i = 0; i < 2; ++i)
                af[i] = *(const bf16x8*)&As[cur][c * 4 + quad][i * 16 + fi][0];
            #pragma unroll
            for (int i = 0; i < 2; ++i)
                #pragma unroll
                for (int j = 0; j < 5; ++j)
                    acc[i][j] = __builtin_amdgcn_mfma_f32_16x16x32_bf16(
                        af[i], bcur[c][j], acc[i][j], 0, 0, 0);
        }
        if (it < 3) {
            bf16x8 pk;
            #pragma unroll
            for (int j = 0; j < 8; ++j) pk[j] = f2bs(xr[j]);
            *(bf16x8*)&As[cur ^ 1][sc8][spx][0] = pk;
            #pragma unroll
            for (int c = 0; c < 2; ++c)
                #pragma unroll
                for (int j = 0; j < 5; ++j) bcur[c][j] = bnxt[c][j];
        }
    }

    bf16* Cp = AH + ((size_t)b * HW_T + p0) * 320;
    #pragma unroll
    for (int i = 0; i < 2; ++i) {
        const int pl = i * 16 + quad * 4;      // local pixel row
        #pragma unroll
        for (int r = 0; r < 4; ++r)
            #pragma unroll
            for (int j = 0; j < 5; ++j)
                Cp[(size_t)(pl + r) * 320 + wn0 + j * 16 + fi] =
                    __float2bfloat16(acc[i][j][r]);
    }
}

// ---------------------------------------------------------------------------
// Fused K4+K5: block = 32-px half-row, 256 threads (4 waves, 8 px/wave).
// Grid 512 (2 blocks/CU). AH (b,p,320) bf16: ch 0..63 = logits (n*16+q),
// ch 64..319 = hv INTERLEAVED (64 + d*4 + n).
// Phase 1 (barrier-free; per-wave P scratch, same-wave DS in-order):
//   softmax over 9 zero-padded window logits; y(16q x 64d) = P(16x36) @
//   HV(36x64) as 4 MFMAs (B-fragments = 2 contiguous b64 loads each) + fp32
//   tail for l=8 (b64 loads); y -> LDS [32][1032] bf16.
// Phase 2: z tile (256 ch x 32 px, K=1024): wave owns 64 ch; A from qwF
//   (fragment layout, register prefetch), B via ds_read_b128 from yL.
//   Single barrier between phases.
// ---------------------------------------------------------------------------
#define YPAD 1032
#define ATTN_LDS (32 * YPAD * 2 + 4 * 9 * 64 * 4)   // 66048 + 9216 = 75264

__global__ __launch_bounds__(256) void attn_qy(
    const bf16* __restrict__ AH, const float* __restrict__ head_b,
    const bf16* __restrict__ qwF, const float* __restrict__ q_b,
    float* __restrict__ z)
{
    extern __shared__ __align__(16) char smem[];
    bf16*  yL = (bf16*)smem;                             // [32][YPAD]
    float* Pm = (float*)(smem + 32 * YPAD * 2) + (threadIdx.x >> 6) * 9 * 64;

    const int tid  = threadIdx.x;
    const int wave = tid >> 6, lane = tid & 63;
    const int half = blockIdx.x & 1;
    const int h    = (blockIdx.x >> 1) & 63;
    const int b    = blockIdx.x >> 7;
    const int w0   = half * 32;
    const int hw0  = h * 64 + w0;
    const int fi = lane & 15, quad = lane >> 4;
    const ushort* AHu = (const ushort*)AH;

    float hb[4];
    #pragma unroll
    for (int dt = 0; dt < 4; ++dt) hb[dt] = head_b[dt * 16 + fi];

    // ---------------- phase 1 (barrier-free) ----------------
    for (int pi = 0; pi < 8; ++pi) {
        const int lp = wave * 8 + pi;      // local pixel 0..31
        const int w  = w0 + lp;
        int off[9]; float okf[9];
        #pragma unroll
        for (int l = 0; l < 9; ++l) {
            const int i = l / 3, j = l % 3;
            const int hh = h + i - 1, ww = w + j - 1;
            const bool ok = ((unsigned)hh < 64u) && ((unsigned)ww < 64u);
            off[l] = ((b << 12) + (ok ? hh : h) * 64 + (ok ? ww : w)) * 320;
            okf[l] = ok ? 1.0f : 0.0f;
        }
        {   // softmax over zero-padded logits (lane = n*16+q)
            float lg[9];
            #pragma unroll
            for (int l = 0; l < 9; ++l)
                lg[l] = bs2f(AHu[(size_t)off[l] + lane]) * okf[l];
            float m = lg[0];
            #pragma unroll
            for (int l = 1; l < 9; ++l) m = fmaxf(m, lg[l]);
            float e[9], s = 0.f;
            #pragma unroll
            for (int l = 0; l < 9; ++l) { e[l] = __expf(lg[l] - m); s += e[l]; }
            const float inv = 1.0f / s;
            #pragma unroll
            for (int l = 0; l < 9; ++l) Pm[l * 64 + lane] = e[l] * inv * okf[l];
        }
        // same-wave DS write->read is in-order; no barrier needed

        // A-fragment: P[q=fi][k=quad*8+j], k=(l,n): l=k>>2, n=k&3 (l<8)
        bf16x8 afr;
        #pragma unroll
        for (int j = 0; j < 8; ++j) {
            const int k = quad * 8 + j;
            afr[j] = f2bs(Pm[(k >> 2) * 64 + (k & 3) * 16 + fi]);
        }
        f32x4 acc[4];
        #pragma unroll
        for (int dt = 0; dt < 4; ++dt) {
            acc[dt][0] = hb[dt]; acc[dt][1] = hb[dt];
            acc[dt][2] = hb[dt]; acc[dt][3] = hb[dt];
        }
        #pragma unroll
        for (int dt = 0; dt < 4; ++dt) {
            const int d = dt * 16 + fi;
            // HV interleaved: rows 64 + d*4 + n -> n=0..3 contiguous (b64)
            const ushort4 u0 = *(const ushort4*)&AHu[(size_t)off[quad * 2]     + 64 + d * 4];
            const ushort4 u1 = *(const ushort4*)&AHu[(size_t)off[quad * 2 + 1] + 64 + d * 4];
            bf16x8 bfr;
            bfr[0] = (short)u0.x; bfr[1] = (short)u0.y;
            bfr[2] = (short)u0.z; bfr[3] = (short)u0.w;
            bfr[4] = (short)u1.x; bfr[5] = (short)u1.y;
            bfr[6] = (short)u1.z; bfr[7] = (short)u1.w;
            acc[dt] = __builtin_amdgcn_mfma_f32_16x16x32_bf16(afr, bfr, acc[dt], 0, 0, 0);
        }
        // tail: l = 8, fp32
        {
            float pv[4][4];
            #pragma unroll
            for (int n = 0; n < 4; ++n)
                #pragma unroll
                for (int r = 0; r < 4; ++r)
                    pv[n][r] = Pm[8 * 64 + n * 16 + quad * 4 + r];
            #pragma unroll
            for (int dt = 0; dt < 4; ++dt) {
                const int d = dt * 16 + fi;
                const ushort4 u = *(const ushort4*)&AHu[(size_t)off[8] + 64 + d * 4];
                const float h0 = bs2f(u.x), h1 = bs2f(u.y), h2 = bs2f(u.z), h3 = bs2f(u.w);
                #pragma unroll
                for (int r = 0; r < 4; ++r) {
                    float a = acc[dt][r];
                    a = fmaf(pv[0][r], h0, a);
                    a = fmaf(pv[1][r], h1, a);
                    a = fmaf(pv[2][r], h2, a);
                    a = fmaf(pv[3][r], h3, a);
                    acc[dt][r] = a;
                }
            }
        }
        // y -> LDS: yL[lp][(quad*4+r)*64 + dt*16+fi]
        #pragma unroll
        for (int dt = 0; dt < 4; ++dt)
            #pragma unroll
            for (int r = 0; r < 4; ++r)
                yL[(size_t)lp * YPAD + (quad * 4 + r) * 64 + dt * 16 + fi] =
                    __float2bfloat16(acc[dt][r]);
    }
    __syncthreads();   // y tile complete (cross-wave)

    // ---------------- phase 2: z = qw @ y^T + q_b ----------------
    f32x4 zacc[4][2] = {};
    bf16x8 af[4], afn[4];
    #pragma unroll
    for (int i = 0; i < 4; ++i)
        af[i] = *(const bf16x8*)&qwF[((size_t)quad * 256 + wave * 64 + i * 16 + fi) * 8];

    #pragma unroll 2
    for (int k0 = 0; k0 < 1024; k0 += 32) {
        if (k0 < 992) {
            const size_t kb = (size_t)((k0 + 32) >> 3) + quad;
            #pragma unroll
            for (int i = 0; i < 4; ++i)
                afn[i] = *(const bf16x8*)&qwF[(kb * 256 + wave * 64 + i * 16 + fi) * 8];
        }
        bf16x8 bfr[2];
        #pragma unroll
        for (int j = 0; j < 2; ++j)
            bfr[j] = *(const bf16x8*)&yL[(size_t)(j * 16 + fi) * YPAD + k0 + quad * 8];
        #pragma unroll
        for (int i = 0; i < 4; ++i)
            #pragma unroll
            for (int j = 0; j < 2; ++j)
                zacc[i][j] = __builtin_amdgcn_mfma_f32_16x16x32_bf16(
                    af[i], bfr[j], zacc[i][j], 0, 0, 0);
        #pragma unroll
        for (int i = 0; i < 4; ++i) af[i] = afn[i];
    }

    #pragma unroll
    for (int i = 0; i < 4; ++i) {
        const int row0 = wave * 64 + i * 16 + quad * 4;
        #pragma unroll
        for (int r = 0; r < 4; ++r) {
            const float bv = q_b[row0 + r];
            #pragma unroll
            for (int j = 0; j < 2; ++j)
                z[((size_t)(b * 256 + row0 + r)) * HW_T + hw0 + j * 16 + fi] =
                    zacc[i][j][r] + bv;
        }
    }
}

// ---------------------------------------------------------------------------
extern "C" void kernel_launch(void* const* d_in, const int* in_sizes, int n_in,
                              void* d_out, int out_size, void* d_ws, size_t ws_size,
                              hipStream_t stream) {
    (void)in_sizes; (void)n_in; (void)out_size; (void)ws_size;
    const float* x      = (const float*)d_in[0];   // (4,256,64,64)
    const float* kv_w   = (const float*)d_in[1];   // (512,256)
    const float* dot_w  = (const float*)d_in[2];   // (4,16,64)
    const float* head_w = (const float*)d_in[3];   // (64,256)
    const float* head_b = (const float*)d_in[4];   // (64,)
    const float* q_w    = (const float*)d_in[5];   // (256,1024)
    const float* q_b    = (const float*)d_in[6];   // (256,)
    float* z = (float*)d_out;                      // (4,256,64,64)

    // workspace (11.2 MB):
    //   AH   bf16 (B,4096,320) 10485760 B @ 0
    //   qwF  bf16 (128,256,8)    524288 B @ 10485760
    //   Wf   bf16 (32,320,8)     163840 B @ 11010048
    char* ws   = (char*)d_ws;
    bf16*  AH  = (bf16*)ws;
    bf16*  qwF = (bf16*)(ws + 10485760);
    bf16*  Wf  = (bf16*)(ws + 11010048);

    // opt-in to >64KB dynamic LDS for the fused kernel (idempotent, host-side)
    static bool attr_done = []() {
        hipFuncSetAttribute((const void*)attn_qy,
                            hipFuncAttributeMaxDynamicSharedMemorySize, ATTN_LDS);
        return true;
    }();
    (void)attr_done;

    fuse_all<<<dim3(448), 256, 0, stream>>>(kv_w, dot_w, head_w, q_w, Wf, qwF);

    // K1: AH = x^T @ W^T  (M=4096/batch, N=320, K=256), transpose fused, bf16 out
    gemm_xw<<<dim3(128, B_T), 256, 0, stream>>>(x, Wf, AH);

    // K4+K5 fused: softmax/apply + z = qw @ y^T + q_b (y never leaves LDS)
    attn_qy<<<dim3(512), 256, ATTN_LDS, stream>>>(AH, head_b, qwF, q_b, z);
}